// Round 4
// baseline (370.817 us; speedup 1.0000x reference)
//
#include <hip/hip_runtime.h>

#define EDIM 10
#define TDIM 50
#define BATCH 65536

// Collapsed weights, two delivery paths:
//   g_cwA[384]: lane-distributed readlane source (6 VGPRs x 64 lanes)
//     [g*100 + k*10 + j] = A_g[k][j] = (Wi_g @ Ws_g)[k][j]     g: 0=r,1=z,2=h
//     [300 + g*10 + j]   = bias_g[j] = (bi_g @ Ws_g + bs_g)[j]
//     [330..383]         = pad
//   g_cwB[304]: per-lane full VGPR copy (300 floats -> 300 VGPRs, constant-indexed)
//     [g*100 + k*10 + j] = B_g[k][j] = (Wh_g @ Ws_g)[k][j]
__device__ __align__(16) float g_cwA[384];
__device__ __align__(16) float g_cwB[304];

__device__ __forceinline__ float fast_sigmoid(float x) {
    float e = __expf(-x);
    return __builtin_amdgcn_rcpf(1.0f + e);
}
__device__ __forceinline__ float fast_tanh(float x) {
    float e = __expf(2.0f * x);
    return 1.0f - 2.0f * __builtin_amdgcn_rcpf(e + 1.0f);
}

// wave-uniform weight broadcast from lane-distributed VGPRs (compile-time lane)
#define RL(i) __uint_as_float(__builtin_amdgcn_readlane( \
                  __float_as_uint(wreg[(i) >> 6]), (i) & 63))
// launder: blocks LICM from hoisting loop-invariant readlanes out of the
// t-loop (no SGPR budget for 330 of them). Proven in earlier rounds.
#define FENCEW() asm volatile("" : "+v"(wreg[0]), "+v"(wreg[1]), "+v"(wreg[2]), \
    "+v"(wreg[3]), "+v"(wreg[4]), "+v"(wreg[5]))

__global__ void collapse_weights(
    const float* __restrict__ Wi_r, const float* __restrict__ bi_r,
    const float* __restrict__ Wh_r, const float* __restrict__ Ws_r, const float* __restrict__ bs_r,
    const float* __restrict__ Wi_z, const float* __restrict__ bi_z,
    const float* __restrict__ Wh_z, const float* __restrict__ Ws_z, const float* __restrict__ bs_z,
    const float* __restrict__ Wi_h, const float* __restrict__ bi_h,
    const float* __restrict__ Wh_h, const float* __restrict__ Wt_h, const float* __restrict__ bt_h)
{
    // A + biases (readlane layout)
    for (int s = threadIdx.x; s < 384; s += 256) {
        float v = 0.0f;
        if (s < 300) {
            int g = s / 100, k = (s % 100) / 10, j = s % 10;
            const float* Wi = (g == 0) ? Wi_r : (g == 1) ? Wi_z : Wi_h;
            const float* Ws = (g == 0) ? Ws_r : (g == 1) ? Ws_z : Wt_h;
            #pragma unroll
            for (int jj = 0; jj < 10; jj++) v += Wi[k * 10 + jj] * Ws[jj * 10 + j];
        } else if (s < 330) {
            int g = (s - 300) / 10, j = (s - 300) % 10;
            const float* Ws = (g == 0) ? Ws_r : (g == 1) ? Ws_z : Wt_h;
            const float* bi = (g == 0) ? bi_r : (g == 1) ? bi_z : bi_h;
            const float* bs = (g == 0) ? bs_r : (g == 1) ? bs_z : bt_h;
            v = bs[j];
            #pragma unroll
            for (int jj = 0; jj < 10; jj++) v += bi[jj] * Ws[jj * 10 + j];
        }
        g_cwA[s] = v;
    }
    // B (per-lane VGPR cache layout)
    for (int s = threadIdx.x; s < 304; s += 256) {
        float v = 0.0f;
        if (s < 300) {
            int g = s / 100, k = (s % 100) / 10, j = s % 10;
            const float* Wh = (g == 0) ? Wh_r : (g == 1) ? Wh_z : Wh_h;
            const float* Ws = (g == 0) ? Ws_r : (g == 1) ? Ws_z : Wt_h;
            #pragma unroll
            for (int jj = 0; jj < 10; jj++) v += Wh[k * 10 + jj] * Ws[jj * 10 + j];
        }
        g_cwB[s] = v;
    }
}

__global__ __launch_bounds__(256, 1) void augru_main(
    const float* __restrict__ x_all, const float* __restrict__ a_all,
    const float* __restrict__ h0,
    float* __restrict__ out)
{
    const int lane = threadIdx.x & 63;
    const int row  = blockIdx.x * 256 + threadIdx.x;   // one FULL row per lane

    // --- lane-distributed A+bias (6 VGPRs). Laundered index: the load must be
    // a vector load into VGPRs, not SMEM (round-2 trap: out-of-order s_load
    // returns force full lgkmcnt drains).
    float wreg[6];
    {
        int lofs = 0;
        asm volatile("" : "+v"(lofs));
        #pragma unroll
        for (int i = 0; i < 6; i++) wreg[i] = g_cwA[i * 64 + lane + lofs];
    }

    // --- full per-lane copy of the B matrices: 300 VGPRs, all indices
    // compile-time after unroll (rule: runtime-indexed arrays go to scratch).
    float Bv[300];
    {
        int lofs = 0;
        asm volatile("" : "+v"(lofs));
        const float* bp = (const float*)g_cwB + lofs;
        #pragma unroll
        for (int i = 0; i < 75; i++) {
            float4 v = *(const float4*)(bp + 4 * i);
            Bv[4 * i + 0] = v.x; Bv[4 * i + 1] = v.y;
            Bv[4 * i + 2] = v.z; Bv[4 * i + 3] = v.w;
        }
    }

    const float2* xp = (const float2*)(x_all + (size_t)row * (TDIM * EDIM));
    const float2* ap = (const float2*)(a_all + (size_t)row * (TDIM * EDIM));

    float h[10];
    #pragma unroll
    for (int j = 0; j < 10; j++) h[j] = h0[j];   // uniform -> scalar loads (once)

    float xc[10], ac[10];
    #pragma unroll
    for (int i = 0; i < 5; i++) {
        float2 v = xp[i]; xc[2 * i] = v.x; xc[2 * i + 1] = v.y;
        float2 u = ap[i]; ac[2 * i] = u.x; ac[2 * i + 1] = u.y;
    }

    #pragma unroll 1
    for (int t = 0; t < TDIM; t++) {
        // branchless 1-step-lookahead prefetch (clamped); ~2000cy of compute
        // below covers the HBM latency.
        int tn = (t < TDIM - 1) ? (t + 1) : t;
        float xn[10], an[10];
        #pragma unroll
        for (int i = 0; i < 5; i++) {
            float2 v = xp[tn * 5 + i]; xn[2 * i] = v.x; xn[2 * i + 1] = v.y;
            float2 u = ap[tn * 5 + i]; an[2 * i] = u.x; an[2 * i + 1] = u.y;
        }

        // ---- biases (readlane) ----
        float ur[10], uz[10], uh[10];
        FENCEW();
        #pragma unroll
        for (int j = 0; j < 10; j++) {
            ur[j] = RL(300 + j); uz[j] = RL(310 + j); uh[j] = RL(320 + j);
        }

        // ---- x-path: readlane-broadcast A weights (scalar operand of v_fma) ----
        FENCEW();
        #pragma unroll
        for (int k = 0; k < 10; k++) {          // x @ A_r
            float xk = xc[k];
            #pragma unroll
            for (int j = 0; j < 10; j++) ur[j] = fmaf(xk, RL(0 + k * 10 + j), ur[j]);
        }
        FENCEW();
        #pragma unroll
        for (int k = 0; k < 10; k++) {          // x @ A_z
            float xk = xc[k];
            #pragma unroll
            for (int j = 0; j < 10; j++) uz[j] = fmaf(xk, RL(100 + k * 10 + j), uz[j]);
        }
        FENCEW();
        #pragma unroll
        for (int k = 0; k < 10; k++) {          // x @ A_h
            float xk = xc[k];
            #pragma unroll
            for (int j = 0; j < 10; j++) uh[j] = fmaf(xk, RL(200 + k * 10 + j), uh[j]);
        }

        // ---- recurrence path: pure VGPR FMAs (weights resident per-lane) ----
        #pragma unroll
        for (int k = 0; k < 10; k++) {          // h @ B_r
            float hk = h[k];
            #pragma unroll
            for (int j = 0; j < 10; j++) ur[j] = fmaf(hk, Bv[0 + k * 10 + j], ur[j]);
        }
        #pragma unroll
        for (int k = 0; k < 10; k++) {          // h @ B_z
            float hk = h[k];
            #pragma unroll
            for (int j = 0; j < 10; j++) uz[j] = fmaf(hk, Bv[100 + k * 10 + j], uz[j]);
        }

        float hz[10];
        #pragma unroll
        for (int j = 0; j < 10; j++) hz[j] = h[j] * fast_sigmoid(uz[j]);

        #pragma unroll
        for (int k = 0; k < 10; k++) {          // (h*z) @ B_h
            float hk = hz[k];
            #pragma unroll
            for (int j = 0; j < 10; j++) uh[j] = fmaf(hk, Bv[200 + k * 10 + j], uh[j]);
        }

        #pragma unroll
        for (int j = 0; j < 10; j++) {
            float r  = fast_sigmoid(ur[j]);
            float hc = fast_tanh(uh[j]);
            float Ra = ac[j] * r;
            h[j] = fmaf(Ra, hc - h[j], h[j]);
        }

        #pragma unroll
        for (int j = 0; j < 10; j++) { xc[j] = xn[j]; ac[j] = an[j]; }
    }

    // lane L writes bytes [40L, 40L+40) -> wave store fully contiguous
    float2* orow = (float2*)(out + (size_t)row * EDIM);
    #pragma unroll
    for (int i = 0; i < 5; i++) orow[i] = make_float2(h[2 * i], h[2 * i + 1]);
}

extern "C" void kernel_launch(void* const* d_in, const int* in_sizes, int n_in,
                              void* d_out, int out_size, void* d_ws, size_t ws_size,
                              hipStream_t stream) {
    collapse_weights<<<1, 256, 0, stream>>>(
        (const float*)d_in[3],  (const float*)d_in[4],  (const float*)d_in[5],
        (const float*)d_in[6],  (const float*)d_in[7],
        (const float*)d_in[8],  (const float*)d_in[9],  (const float*)d_in[10],
        (const float*)d_in[11], (const float*)d_in[12],
        (const float*)d_in[13], (const float*)d_in[14], (const float*)d_in[15],
        (const float*)d_in[16], (const float*)d_in[17]);
    augru_main<<<BATCH / 256, 256, 0, stream>>>(
        (const float*)d_in[0], (const float*)d_in[1], (const float*)d_in[2],
        (float*)d_out);
}